// Round 10
// baseline (2571.974 us; speedup 1.0000x reference)
//
#include <hip/hip_runtime.h>
#include <stdint.h>

// ---------------- constants ----------------
static const size_t OFF_ATT = 20480;    // out: 1024*10*2
static const size_t OFF_H   = 122880;   // + att 1024*10*10
static const size_t OFF_C   = 385024;   // + h 2*1024*128

typedef _Float16 f16;
typedef f16 f16x8 __attribute__((ext_vector_type(8)));
typedef float f32x4 __attribute__((ext_vector_type(4)));

__device__ __forceinline__ float sigf(float x) { return 1.0f / (1.0f + __expf(-x)); }
// tanh(x) = 1 - 2/(e^{2x}+1); safe at +/-inf, ~1e-7 abs err.
__device__ __forceinline__ float tanhfast(float x) { return 1.0f - 2.0f / (__expf(2.0f * x) + 1.0f); }

#define MFMA16(a, b, c) __builtin_amdgcn_mfma_f32_16x16x32_f16((a), (b), (c), 0, 0, 0)

// ---------------- prep kernels ----------------
__global__ void bias_comb_k(const float* __restrict__ bih, const float* __restrict__ bhh,
                            float* __restrict__ b0, float* __restrict__ b1) {
    int i = blockIdx.x * 256 + threadIdx.x;
    if (i < 512) {
        b0[i] = bih[i] + bhh[i];
        b1[i] = bih[512 + i] + bhh[512 + i];
    }
}

// pack f32 W[N][K] (row-major) into f16 B-fragment-linear buffer:
// out[((nt*(K/32)+kt)*64 + lane)*8 + i] = W[nt*16 + (lane&15)][kt*32 + (lane>>4)*8 + i]
__global__ __launch_bounds__(256) void pack_frag_k(const float* __restrict__ W, f16* __restrict__ out,
                                                   int N, int K) {
    int idx = blockIdx.x * 256 + threadIdx.x;
    if (idx >= N * K) return;
    int i = idx & 7, l = (idx >> 3) & 63, rest = idx >> 9;
    int KT = K >> 5;
    int kt = rest % KT, nt = rest / KT;
    int n = nt * 16 + (l & 15);
    int k = kt * 32 + (l >> 4) * 8 + i;
    out[idx] = (f16)W[n * K + k];
}

// xg0[b][t][512] -> xgr[blk][t][col][row16]  (frag-friendly C-init layout)
__global__ __launch_bounds__(256) void reshape_xg_k(const float* __restrict__ xg0, float* __restrict__ xgr) {
    int idx = blockIdx.x * 256 + threadIdx.x;     // 64*10*512*16 = 5242880
    int row16 = idx & 15;
    int col   = (idx >> 4) & 511;
    int tb    = idx >> 13;         // blk*10 + t
    int t     = tb % 10, blk = tb / 10;
    xgr[idx] = xg0[(((size_t)(blk * 16 + row16) * 10 + t) << 9) + col];
}

// ---------------- tiled GEMM: C = act(A[M,K] @ B[N,K]^T + bias[N]) ----------------
__global__ __launch_bounds__(256) void gemm_bias_act_k(const float* __restrict__ A, const float* __restrict__ Bm,
                                                       const float* __restrict__ bias, float* __restrict__ C,
                                                       int M, int N, int K, int relu) {
    __shared__ float As[16][68];
    __shared__ float Bs[16][68];
    int tid = threadIdx.x;
    int tx = tid & 15, ty = tid >> 4;
    int bm = blockIdx.y << 6, bn = blockIdx.x << 6;
    int lr = tid >> 2, lk = (tid & 3) << 2;
    float acc[4][4] = {};
    for (int k0 = 0; k0 < K; k0 += 16) {
        __syncthreads();
        float4 av = *(const float4*)(A + (size_t)(bm + lr) * K + k0 + lk);
        float4 bv = *(const float4*)(Bm + (size_t)(bn + lr) * K + k0 + lk);
        As[lk + 0][lr] = av.x; As[lk + 1][lr] = av.y; As[lk + 2][lr] = av.z; As[lk + 3][lr] = av.w;
        Bs[lk + 0][lr] = bv.x; Bs[lk + 1][lr] = bv.y; Bs[lk + 2][lr] = bv.z; Bs[lk + 3][lr] = bv.w;
        __syncthreads();
#pragma unroll
        for (int kk = 0; kk < 16; ++kk) {
            float a[4], b[4];
#pragma unroll
            for (int i = 0; i < 4; ++i) a[i] = As[kk][ty * 4 + i];
#pragma unroll
            for (int j = 0; j < 4; ++j) b[j] = Bs[kk][tx * 4 + j];
#pragma unroll
            for (int i = 0; i < 4; ++i)
#pragma unroll
                for (int j = 0; j < 4; ++j) acc[i][j] = fmaf(a[i], b[j], acc[i][j]);
        }
    }
#pragma unroll
    for (int i = 0; i < 4; ++i)
#pragma unroll
        for (int j = 0; j < 4; ++j) {
            float v = acc[i][j] + bias[bn + tx * 4 + j];
            if (relu) v = fmaxf(v, 0.0f);
            C[(size_t)(bm + ty * 4 + i) * N + bn + tx * 4 + j] = v;
        }
}

// ---------------- main MFMA recurrent kernel ----------------
// 64 blocks x 512 threads (8 waves, 2/SIMD, <=256 unified VGPR+AGPR). Block owns
// 16 batch rows. Wave w owns gate cols [16w,16w+16) of each gate quadrant.
// ALL weights persist in registers (48 B-frags = 192 regs, MFMA-B-operand only
// -> AGPR-eligible). h state lives ONLY in LDS (f16, double-buffered, swizzled);
// c state in 8 f32 regs. ONE barrier per step (dbuf ordering proof in session
// notes: every cross-wave RAW/WAR pair is ordered by the NEXT mid-step barrier).
// K[hist] + V-head computed incrementally at hist-end (M history not stored).
__global__ __launch_bounds__(512, 2) void recurrent_mfma2_k(
    const float* __restrict__ xgr,     // [blk][t][col512][row16] f32
    const f16* __restrict__ Wf,        // 3 mats x 512x128 f16 frag-linear (Whh0, Wih1, Whh1)
    const float* __restrict__ bias1,   // [512] bih1+bhh1
    const f16* __restrict__ Wqf, const float* __restrict__ bq,
    const f16* __restrict__ Wkf, const float* __restrict__ bk,
    const f16* __restrict__ Wo1f, const float* __restrict__ bo1,
    const float* __restrict__ Wo2, const float* __restrict__ bo2,
    const float* __restrict__ gv, const float* __restrict__ uv,
    float* __restrict__ out) {
    __shared__ __align__(16) f16 hA0[2][2048];    // 16 rows x 128, XOR-swizzled, dbuf
    __shared__ __align__(16) f16 hA1[2][2048];
    __shared__ __align__(16) f16 Ksh[10][16 * 136];
    __shared__ float vsh[10][16][2];              // log-softmax'd V per hist
    __shared__ __align__(16) float qsm[16 * 132];
    __shared__ __align__(16) float us[16 * 68];
    __shared__ float scs[16][10];
    __shared__ float wo2s[130];

    const int tid  = threadIdx.x;
    const int lane = tid & 63;
    const int w    = tid >> 6;        // wave id 0..7
    const int ml   = lane & 15;       // tile row (A/m) / tile col (B/n, D col)
    const int qh   = lane >> 4;       // lane quad -> k-group / D row group
    const int blk  = blockIdx.x;
    const int b0   = blk << 4;

    if (tid < 128) wo2s[tid] = Wo2[tid];
    if (tid < 2)   wo2s[128 + tid] = bo2[tid];

    // ---- persistent weight fragments (B-operand only -> AGPRs) ----
    // frag(nt=g*8+w, kt) at g*16384 + w*2048 + kt*512 + lane*8
    f16x8 W0[4][4], W1[4][4], W2[4][4];
#pragma unroll
    for (int g = 0; g < 4; ++g)
#pragma unroll
        for (int kt = 0; kt < 4; ++kt) {
            int off = g * 16384 + w * 2048 + kt * 512 + lane * 8;
            W0[g][kt] = *(const f16x8*)(Wf + off);
            W1[g][kt] = *(const f16x8*)(Wf + 65536 + off);
            W2[g][kt] = *(const f16x8*)(Wf + 131072 + off);
        }
    float bs1v[4];
#pragma unroll
    for (int g = 0; g < 4; ++g) bs1v[g] = bias1[g * 128 + w * 16 + ml];

    // ---- state init ----
    float c0v[4], c1v[4];
#pragma unroll
    for (int r4 = 0; r4 < 4; ++r4) {
        int row = qh * 4 + r4;
        int b = b0 + row, hj = w * 16 + ml;
        c0v[r4] = uv[(size_t)b * 128 + hj];
        c1v[r4] = uv[131072 + (size_t)b * 128 + hj];
        int ke = hj ^ ((row & 7) << 3);
        hA0[0][row * 128 + ke] = (f16)gv[(size_t)b * 128 + hj];
        hA1[0][row * 128 + ke] = (f16)gv[131072 + (size_t)b * 128 + hj];
    }
    int p = 0;
    __syncthreads();

    // A-frag read: lane reads A[m=ml][k = kt*32 + qh*8 .. +8] from swizzled tile
    auto readA = [&](const f16* base, int kt) -> f16x8 {
        int e = ml * 128 + (((kt << 5) + (qh << 3)) ^ ((ml & 7) << 3));
        return *(const f16x8*)(base + e);
    };

    auto lstm_step = [&](int t) {
        // ---------- layer 0: gates = h0 @ Whh0^T + xg0 (C-init) ----------
        f32x4 C0, C1, C2, C3;
        {
            const float* xb = xgr + ((((size_t)blk * 10 + t) << 9) << 4);
            int coff = w * 16 + ml;
            C0 = *(const f32x4*)(xb + ((coff      ) << 4) + qh * 4);
            C1 = *(const f32x4*)(xb + ((coff + 128) << 4) + qh * 4);
            C2 = *(const f32x4*)(xb + ((coff + 256) << 4) + qh * 4);
            C3 = *(const f32x4*)(xb + ((coff + 384) << 4) + qh * 4);
        }
        const f16* h0p = &hA0[p][0];
#pragma unroll
        for (int kt = 0; kt < 4; ++kt) {
            f16x8 a = readA(h0p, kt);
            C0 = MFMA16(a, W0[0][kt], C0);
            C1 = MFMA16(a, W0[1][kt], C1);
            C2 = MFMA16(a, W0[2][kt], C2);
            C3 = MFMA16(a, W0[3][kt], C3);
        }
        f16* h0n = &hA0[p ^ 1][0];
#pragma unroll
        for (int r4 = 0; r4 < 4; ++r4) {
            float cn = sigf(C1[r4]) * c0v[r4] + sigf(C0[r4]) * tanhfast(C2[r4]);
            float hn = sigf(C3[r4]) * tanhfast(cn);
            c0v[r4] = cn;
            int row = qh * 4 + r4;
            h0n[row * 128 + ((w * 16 + ml) ^ ((row & 7) << 3))] = (f16)hn;
        }
        __syncthreads();   // the ONLY barrier per step
        // ---------- layer 1: gates = h0new @ Wih1^T + h1 @ Whh1^T + bias1 ----------
        C0 = f32x4{bs1v[0], bs1v[0], bs1v[0], bs1v[0]};
        C1 = f32x4{bs1v[1], bs1v[1], bs1v[1], bs1v[1]};
        C2 = f32x4{bs1v[2], bs1v[2], bs1v[2], bs1v[2]};
        C3 = f32x4{bs1v[3], bs1v[3], bs1v[3], bs1v[3]};
#pragma unroll
        for (int kt = 0; kt < 4; ++kt) {
            f16x8 a = readA(h0n, kt);
            C0 = MFMA16(a, W1[0][kt], C0);
            C1 = MFMA16(a, W1[1][kt], C1);
            C2 = MFMA16(a, W1[2][kt], C2);
            C3 = MFMA16(a, W1[3][kt], C3);
        }
        const f16* h1p = &hA1[p][0];
#pragma unroll
        for (int kt = 0; kt < 4; ++kt) {
            f16x8 a = readA(h1p, kt);
            C0 = MFMA16(a, W2[0][kt], C0);
            C1 = MFMA16(a, W2[1][kt], C1);
            C2 = MFMA16(a, W2[2][kt], C2);
            C3 = MFMA16(a, W2[3][kt], C3);
        }
        f16* h1n = &hA1[p ^ 1][0];
#pragma unroll
        for (int r4 = 0; r4 < 4; ++r4) {
            float cn = sigf(C1[r4]) * c1v[r4] + sigf(C0[r4]) * tanhfast(C2[r4]);
            float hn = sigf(C3[r4]) * tanhfast(cn);
            c1v[r4] = cn;
            int row = qh * 4 + r4;
            h1n[row * 128 + ((w * 16 + ml) ^ ((row & 7) << 3))] = (f16)hn;
        }
        p ^= 1;            // no end-of-step barrier (dbuf + next mid-step barrier order all hazards)
    };

    for (int r = 0; r < 10; ++r) {
        for (int hist = 0; hist <= r; ++hist) {
            const int t0 = (hist <= 1) ? 0 : hist;  // quirk: hist==1 reruns full prefix
            for (int t = t0; t <= r; ++t) lstm_step(t);

            // ---- hist-end: K[hist], u, (Q if last), log-softmax V -> LDS ----
            f16x8 Bk[4], Bo[4], Bq[4];
#pragma unroll
            for (int kt = 0; kt < 4; ++kt) Bk[kt] = *(const f16x8*)(Wkf + (((w * 4 + kt) * 64 + lane) << 3));
            if (w < 4) {
#pragma unroll
                for (int kt = 0; kt < 4; ++kt) Bo[kt] = *(const f16x8*)(Wo1f + (((w * 4 + kt) * 64 + lane) << 3));
            }
            if (hist == r) {
#pragma unroll
                for (int kt = 0; kt < 4; ++kt) Bq[kt] = *(const f16x8*)(Wqf + (((w * 4 + kt) * 64 + lane) << 3));
            }
            const float bkv  = bk[w * 16 + ml];
            const float bo1v = (w < 4) ? bo1[w * 16 + ml] : 0.0f;
            __syncthreads();   // h1 (hA1[p]) visible to all
            const f16* h1c = &hA1[p][0];
            {
                f32x4 C = f32x4{bkv, bkv, bkv, bkv};
#pragma unroll
                for (int kt = 0; kt < 4; ++kt) C = MFMA16(readA(h1c, kt), Bk[kt], C);
#pragma unroll
                for (int r4 = 0; r4 < 4; ++r4) Ksh[hist][(qh * 4 + r4) * 136 + w * 16 + ml] = (f16)C[r4];
            }
            if (w < 4) {
                f32x4 C = f32x4{bo1v, bo1v, bo1v, bo1v};
#pragma unroll
                for (int kt = 0; kt < 4; ++kt) C = MFMA16(readA(h1c, kt), Bo[kt], C);
#pragma unroll
                for (int r4 = 0; r4 < 4; ++r4) us[(qh * 4 + r4) * 68 + w * 16 + ml] = fmaxf(C[r4], 0.f);
            }
            if (hist == r) {
                const float bqv = bq[w * 16 + ml];
                f32x4 C = f32x4{bqv, bqv, bqv, bqv};
#pragma unroll
                for (int kt = 0; kt < 4; ++kt) C = MFMA16(readA(h1c, kt), Bq[kt], C);
#pragma unroll
                for (int r4 = 0; r4 < 4; ++r4) qsm[(qh * 4 + r4) * 132 + w * 16 + ml] = C[r4];
            }
            __syncthreads();   // us / Ksh / qsm visible
            if (tid < 16) {    // V head: v = logsoftmax(u @ Wo2^T + bo2)
                float v0 = wo2s[128], v1 = wo2s[129];
                const float* up = us + tid * 68;
#pragma unroll 8
                for (int k = 0; k < 64; ++k) {
                    float uu = up[k];
                    v0 = fmaf(uu, wo2s[k], v0);
                    v1 = fmaf(uu, wo2s[64 + k], v1);
                }
                float mv = fmaxf(v0, v1);
                float lse = mv + __logf(__expf(v0 - mv) + __expf(v1 - mv));
                vsh[hist][tid][0] = v0 - lse;
                vsh[hist][tid][1] = v1 - lse;
            }
            if (hist == r && tid < 16 * (r + 1)) {   // raw scores (waves 0..2)
                int row = tid & 15, kk = tid >> 4;
                const float* qp = qsm + row * 132;
                const f16* kp = &Ksh[kk][row * 136];
                float pacc = 0.f;
                for (int k = 0; k < 128; ++k) pacc += qp[k] * (float)kp[k];
                scs[row][kk] = pacc * 0.088388347648318447f;   // 1/sqrt(128)
            }
        }
        // ---------------- round-end: softmax + output ----------------
        __syncthreads();
        if (tid < 16) {
            float mx = -3.4e38f;
            for (int kk = 0; kk <= r; ++kk) mx = fmaxf(mx, scs[tid][kk]);
            float sum = 0.f;
            for (int kk = 0; kk <= r; ++kk) sum += __expf(scs[tid][kk] - mx);
            float inv = 1.0f / sum;
            float o0 = 0.f, o1 = 0.f;
            for (int kk = 0; kk <= r; ++kk) {
                float pp = __expf(scs[tid][kk] - mx) * inv;
                scs[tid][kk] = pp;
                o0 = fmaf(pp, vsh[kk][tid][0], o0);
                o1 = fmaf(pp, vsh[kk][tid][1], o1);
            }
            out[(size_t)(b0 + tid) * 20 + r * 2 + 0] = o0;
            out[(size_t)(b0 + tid) * 20 + r * 2 + 1] = o1;
        }
        __syncthreads();
        if (tid < 160) {   // attention output with -1 padding
            int row = tid / 10, jp = tid - row * 10;
            out[OFF_ATT + (size_t)(b0 + row) * 100 + (size_t)r * 10 + jp] = (jp <= r) ? scs[row][jp] : -1.0f;
        }
    }

    // final h (from f16 LDS state), c (f32 regs)
#pragma unroll
    for (int r4 = 0; r4 < 4; ++r4) {
        int row = qh * 4 + r4;
        int b = b0 + row, hj = w * 16 + ml;
        int ke = row * 128 + (hj ^ ((row & 7) << 3));
        out[OFF_H + (size_t)b * 128 + hj]          = (float)hA0[p][ke];
        out[OFF_H + 131072 + (size_t)b * 128 + hj] = (float)hA1[p][ke];
        out[OFF_C + (size_t)b * 128 + hj]          = c0v[r4];
        out[OFF_C + 131072 + (size_t)b * 128 + hj] = c1v[r4];
    }
}

// ---------------- launch ----------------
extern "C" void kernel_launch(void* const* d_in, const int* in_sizes, int n_in,
                              void* d_out, int out_size, void* d_ws, size_t ws_size,
                              hipStream_t stream) {
    const float* input_vec = (const float*)d_in[0];
    const float* gv    = (const float*)d_in[1];
    const float* uv    = (const float*)d_in[2];
    const float* W_in1 = (const float*)d_in[3];
    const float* b_in1 = (const float*)d_in[4];
    const float* W_in2 = (const float*)d_in[5];
    const float* b_in2 = (const float*)d_in[6];
    const float* Wq    = (const float*)d_in[7];
    const float* bq    = (const float*)d_in[8];
    const float* Wk    = (const float*)d_in[9];
    const float* bk    = (const float*)d_in[10];
    const float* Wih   = (const float*)d_in[11];
    const float* Whh   = (const float*)d_in[12];
    const float* bih   = (const float*)d_in[13];
    const float* bhh   = (const float*)d_in[14];
    const float* Wo1   = (const float*)d_in[15];
    const float* bo1   = (const float*)d_in[16];
    const float* Wo2   = (const float*)d_in[17];
    const float* bo2   = (const float*)d_in[18];
    float* out = (float*)d_out;
    float* ws  = (float*)d_ws;

    // workspace layout (float units)
    float* tmp1    = ws + 0;           // [10240][1024] (dead after gemm2)
    float* xg0     = ws + 0;           // [10240][512]  (gemm3 out, over tmp1)
    float* xgr     = ws + 5242880;     // [64][10][512][16] (inside old tmp1 tail)
    float* lstm_in = ws + 10485760;    // [10240][128]
    f16*   Wf      = (f16*)(ws + 11796480);   // 3 x 65536 f16
    f16*   Wqf     = (f16*)(ws + 11894784);   // 16384 f16
    f16*   Wkf     = (f16*)(ws + 11902976);
    f16*   Wo1f    = (f16*)(ws + 11911168);   // 8192 f16
    float* bias1c  = ws + 11915264;    // [512]
    float* bias0c  = ws + 11915776;    // [512]

    // weight fragment packing + bias combine
    pack_frag_k<<<256, 256, 0, stream>>>(Whh,          Wf,           512, 128); // Whh0
    pack_frag_k<<<256, 256, 0, stream>>>(Wih + 65536,  Wf + 65536,   512, 128); // Wih1
    pack_frag_k<<<256, 256, 0, stream>>>(Whh + 65536,  Wf + 131072,  512, 128); // Whh1
    pack_frag_k<<<64,  256, 0, stream>>>(Wq,  Wqf,  128, 128);
    pack_frag_k<<<64,  256, 0, stream>>>(Wk,  Wkf,  128, 128);
    pack_frag_k<<<32,  256, 0, stream>>>(Wo1, Wo1f, 64,  128);
    bias_comb_k<<<2, 256, 0, stream>>>(bih, bhh, bias0c, bias1c);

    // input MLP + layer-0 input-gate precompute (fp32), then frag-layout reshape
    gemm_bias_act_k<<<dim3(16, 160), 256, 0, stream>>>(input_vec, W_in1, b_in1, tmp1, 10240, 1024, 512, 1);
    gemm_bias_act_k<<<dim3(2, 160), 256, 0, stream>>>(tmp1, W_in2, b_in2, lstm_in, 10240, 128, 1024, 1);
    gemm_bias_act_k<<<dim3(8, 160), 256, 0, stream>>>(lstm_in, Wih, bias0c, xg0, 10240, 512, 128, 0);
    reshape_xg_k<<<20480, 256, 0, stream>>>(xg0, xgr);

    recurrent_mfma2_k<<<64, 512, 0, stream>>>(xgr, Wf, bias1c,
                                              Wqf, bq, Wkf, bk, Wo1f, bo1, Wo2, bo2,
                                              gv, uv, out);
}

// Round 14
// 2570.551 us; speedup vs baseline: 1.0006x; 1.0006x over previous
//
#include <hip/hip_runtime.h>
#include <stdint.h>

// ---------------- constants ----------------
static const size_t OFF_ATT = 20480;    // out: 1024*10*2
static const size_t OFF_H   = 122880;   // + att 1024*10*10
static const size_t OFF_C   = 385024;   // + h 2*1024*128

typedef _Float16 f16;
typedef f16 f16x8 __attribute__((ext_vector_type(8)));
typedef float f32x4 __attribute__((ext_vector_type(4)));

__device__ __forceinline__ float sigf(float x) { return 1.0f / (1.0f + __expf(-x)); }
// tanh(x) = 1 - 2/(e^{2x}+1); safe at +/-inf, ~1e-7 abs err.
__device__ __forceinline__ float tanhfast(float x) { return 1.0f - 2.0f / (__expf(2.0f * x) + 1.0f); }

#define MFMA16(a, b, c) __builtin_amdgcn_mfma_f32_16x16x32_f16((a), (b), (c), 0, 0, 0)

// ---------------- prep kernels ----------------
__global__ void bias_comb_k(const float* __restrict__ bih, const float* __restrict__ bhh,
                            float* __restrict__ b0, float* __restrict__ b1) {
    int i = blockIdx.x * 256 + threadIdx.x;
    if (i < 512) {
        b0[i] = bih[i] + bhh[i];
        b1[i] = bih[512 + i] + bhh[512 + i];
    }
}

// pack f32 W[N][K] (row-major) into f16 B-fragment-linear buffer:
// out[((nt*(K/32)+kt)*64 + lane)*8 + i] = W[nt*16 + (lane&15)][kt*32 + (lane>>4)*8 + i]
__global__ __launch_bounds__(256) void pack_frag_k(const float* __restrict__ W, f16* __restrict__ out,
                                                   int N, int K) {
    int idx = blockIdx.x * 256 + threadIdx.x;
    if (idx >= N * K) return;
    int i = idx & 7, l = (idx >> 3) & 63, rest = idx >> 9;
    int KT = K >> 5;
    int kt = rest % KT, nt = rest / KT;
    int n = nt * 16 + (l & 15);
    int k = kt * 32 + (l >> 4) * 8 + i;
    out[idx] = (f16)W[n * K + k];
}

// xg0[b][t][512] -> xgr[blk][t][col][row16]  (frag-friendly C-init layout)
__global__ __launch_bounds__(256) void reshape_xg_k(const float* __restrict__ xg0, float* __restrict__ xgr) {
    int idx = blockIdx.x * 256 + threadIdx.x;     // 64*10*512*16 = 5242880
    int row16 = idx & 15;
    int col   = (idx >> 4) & 511;
    int tb    = idx >> 13;         // blk*10 + t
    int t     = tb % 10, blk = tb / 10;
    xgr[idx] = xg0[(((size_t)(blk * 16 + row16) * 10 + t) << 9) + col];
}

// ---------------- tiled GEMM: C = act(A[M,K] @ B[N,K]^T + bias[N]) ----------------
__global__ __launch_bounds__(256) void gemm_bias_act_k(const float* __restrict__ A, const float* __restrict__ Bm,
                                                       const float* __restrict__ bias, float* __restrict__ C,
                                                       int M, int N, int K, int relu) {
    __shared__ float As[16][68];
    __shared__ float Bs[16][68];
    int tid = threadIdx.x;
    int tx = tid & 15, ty = tid >> 4;
    int bm = blockIdx.y << 6, bn = blockIdx.x << 6;
    int lr = tid >> 2, lk = (tid & 3) << 2;
    float acc[4][4] = {};
    for (int k0 = 0; k0 < K; k0 += 16) {
        __syncthreads();
        float4 av = *(const float4*)(A + (size_t)(bm + lr) * K + k0 + lk);
        float4 bv = *(const float4*)(Bm + (size_t)(bn + lr) * K + k0 + lk);
        As[lk + 0][lr] = av.x; As[lk + 1][lr] = av.y; As[lk + 2][lr] = av.z; As[lk + 3][lr] = av.w;
        Bs[lk + 0][lr] = bv.x; Bs[lk + 1][lr] = bv.y; Bs[lk + 2][lr] = bv.z; Bs[lk + 3][lr] = bv.w;
        __syncthreads();
#pragma unroll
        for (int kk = 0; kk < 16; ++kk) {
            float a[4], b[4];
#pragma unroll
            for (int i = 0; i < 4; ++i) a[i] = As[kk][ty * 4 + i];
#pragma unroll
            for (int j = 0; j < 4; ++j) b[j] = Bs[kk][tx * 4 + j];
#pragma unroll
            for (int i = 0; i < 4; ++i)
#pragma unroll
                for (int j = 0; j < 4; ++j) acc[i][j] = fmaf(a[i], b[j], acc[i][j]);
        }
    }
#pragma unroll
    for (int i = 0; i < 4; ++i)
#pragma unroll
        for (int j = 0; j < 4; ++j) {
            float v = acc[i][j] + bias[bn + tx * 4 + j];
            if (relu) v = fmaxf(v, 0.0f);
            C[(size_t)(bm + ty * 4 + i) * N + bn + tx * 4 + j] = v;
        }
}

// ---------------- main MFMA recurrent kernel ----------------
// R14 = R10 EXACTLY (builtin MFMA, proven absmax 3.9e-3) + the occupancy pin
// that R4/R10 were missing: amdgpu_waves_per_eu(2,2) -> register budget
// 512/2 = 256/thread, enough for 48 f16x8 weight frags (192 regs) + ~60 arch
// regs WITHOUT spill. (R4/R10's VGPR_Count=128 revealed __launch_bounds__'s
// 2nd arg was applied CUDA-style (min blocks/CU): 2 blocks -> 4 waves/SIMD ->
// 128-reg budget -> forced spill. The explicit attribute bypasses that.)
__global__ __attribute__((amdgpu_waves_per_eu(2, 2))) __launch_bounds__(512)
void recurrent_mfma6_k(
    const float* __restrict__ xgr,     // [blk][t][col512][row16] f32
    const f16* __restrict__ Wf,        // 3 mats x 512x128 f16 frag-linear (Whh0, Wih1, Whh1)
    const float* __restrict__ bias1,   // [512] bih1+bhh1
    const f16* __restrict__ Wqf, const float* __restrict__ bq,
    const f16* __restrict__ Wkf, const float* __restrict__ bk,
    const f16* __restrict__ Wo1f, const float* __restrict__ bo1,
    const float* __restrict__ Wo2, const float* __restrict__ bo2,
    const float* __restrict__ gv, const float* __restrict__ uv,
    float* __restrict__ out) {
    __shared__ __align__(16) f16 hA0[2][2048];    // 16 rows x 128, XOR-swizzled, dbuf
    __shared__ __align__(16) f16 hA1[2][2048];
    __shared__ __align__(16) f16 Ksh[10][16 * 136];
    __shared__ float vsh[10][16][2];              // log-softmax'd V per hist
    __shared__ __align__(16) float qsm[16 * 132];
    __shared__ __align__(16) float us[16 * 68];
    __shared__ float scs[16][10];
    __shared__ float wo2s[130];

    const int tid  = threadIdx.x;
    const int lane = tid & 63;
    const int w    = tid >> 6;        // wave id 0..7
    const int ml   = lane & 15;       // tile row (A/m) / tile col (B/n, D col)
    const int qh   = lane >> 4;       // lane quad -> k-group / D row group
    const int blk  = blockIdx.x;
    const int b0   = blk << 4;

    if (tid < 128) wo2s[tid] = Wo2[tid];
    if (tid < 2)   wo2s[128 + tid] = bo2[tid];

    // ---- persistent weight fragments (48 x f16x8 = 192 regs/thread) ----
    // frag(nt=g*8+w, kt) at g*16384 + w*2048 + kt*512 + lane*8
    f16x8 W0[4][4], W1[4][4], W2[4][4];
#pragma unroll
    for (int g = 0; g < 4; ++g)
#pragma unroll
        for (int kt = 0; kt < 4; ++kt) {
            int off = g * 16384 + w * 2048 + kt * 512 + lane * 8;
            W0[g][kt] = *(const f16x8*)(Wf + off);
            W1[g][kt] = *(const f16x8*)(Wf + 65536 + off);
            W2[g][kt] = *(const f16x8*)(Wf + 131072 + off);
        }
    float bs1v[4];
#pragma unroll
    for (int g = 0; g < 4; ++g) bs1v[g] = bias1[g * 128 + w * 16 + ml];

    // ---- state init ----
    float c0v[4], c1v[4];
#pragma unroll
    for (int r4 = 0; r4 < 4; ++r4) {
        int row = qh * 4 + r4;
        int b = b0 + row, hj = w * 16 + ml;
        c0v[r4] = uv[(size_t)b * 128 + hj];
        c1v[r4] = uv[131072 + (size_t)b * 128 + hj];
        int ke = hj ^ ((row & 7) << 3);
        hA0[0][row * 128 + ke] = (f16)gv[(size_t)b * 128 + hj];
        hA1[0][row * 128 + ke] = (f16)gv[131072 + (size_t)b * 128 + hj];
    }
    int p = 0;
    __syncthreads();

    // A-frag read: lane reads A[m=ml][k = kt*32 + qh*8 .. +8] from swizzled tile
    auto readA = [&](const f16* base, int kt) -> f16x8 {
        int e = ml * 128 + (((kt << 5) + (qh << 3)) ^ ((ml & 7) << 3));
        return *(const f16x8*)(base + e);
    };

    auto lstm_step = [&](int t) {
        // ---------- layer 0: gates = h0 @ Whh0^T + xg0 (C-init) ----------
        f32x4 C0, C1, C2, C3;
        {
            const float* xb = xgr + ((((size_t)blk * 10 + t) << 9) << 4);
            int coff = w * 16 + ml;
            C0 = *(const f32x4*)(xb + ((coff      ) << 4) + qh * 4);
            C1 = *(const f32x4*)(xb + ((coff + 128) << 4) + qh * 4);
            C2 = *(const f32x4*)(xb + ((coff + 256) << 4) + qh * 4);
            C3 = *(const f32x4*)(xb + ((coff + 384) << 4) + qh * 4);
        }
        const f16* h0p = &hA0[p][0];
#pragma unroll
        for (int kt = 0; kt < 4; ++kt) {
            f16x8 a = readA(h0p, kt);
            C0 = MFMA16(a, W0[0][kt], C0);
            C1 = MFMA16(a, W0[1][kt], C1);
            C2 = MFMA16(a, W0[2][kt], C2);
            C3 = MFMA16(a, W0[3][kt], C3);
        }
        f16* h0n = &hA0[p ^ 1][0];
#pragma unroll
        for (int r4 = 0; r4 < 4; ++r4) {
            float cn = sigf(C1[r4]) * c0v[r4] + sigf(C0[r4]) * tanhfast(C2[r4]);
            float hn = sigf(C3[r4]) * tanhfast(cn);
            c0v[r4] = cn;
            int row = qh * 4 + r4;
            h0n[row * 128 + ((w * 16 + ml) ^ ((row & 7) << 3))] = (f16)hn;
        }
        __syncthreads();   // the ONLY barrier per step
        // ---------- layer 1: gates = h0new @ Wih1^T + h1 @ Whh1^T + bias1 ----------
        C0 = f32x4{bs1v[0], bs1v[0], bs1v[0], bs1v[0]};
        C1 = f32x4{bs1v[1], bs1v[1], bs1v[1], bs1v[1]};
        C2 = f32x4{bs1v[2], bs1v[2], bs1v[2], bs1v[2]};
        C3 = f32x4{bs1v[3], bs1v[3], bs1v[3], bs1v[3]};
#pragma unroll
        for (int kt = 0; kt < 4; ++kt) {
            f16x8 a = readA(h0n, kt);
            C0 = MFMA16(a, W1[0][kt], C0);
            C1 = MFMA16(a, W1[1][kt], C1);
            C2 = MFMA16(a, W1[2][kt], C2);
            C3 = MFMA16(a, W1[3][kt], C3);
        }
        const f16* h1p = &hA1[p][0];
#pragma unroll
        for (int kt = 0; kt < 4; ++kt) {
            f16x8 a = readA(h1p, kt);
            C0 = MFMA16(a, W2[0][kt], C0);
            C1 = MFMA16(a, W2[1][kt], C1);
            C2 = MFMA16(a, W2[2][kt], C2);
            C3 = MFMA16(a, W2[3][kt], C3);
        }
        f16* h1n = &hA1[p ^ 1][0];
#pragma unroll
        for (int r4 = 0; r4 < 4; ++r4) {
            float cn = sigf(C1[r4]) * c1v[r4] + sigf(C0[r4]) * tanhfast(C2[r4]);
            float hn = sigf(C3[r4]) * tanhfast(cn);
            c1v[r4] = cn;
            int row = qh * 4 + r4;
            h1n[row * 128 + ((w * 16 + ml) ^ ((row & 7) << 3))] = (f16)hn;
        }
        p ^= 1;            // no end-of-step barrier (dbuf + next mid-step barrier order hazards)
    };

    for (int r = 0; r < 10; ++r) {
        for (int hist = 0; hist <= r; ++hist) {
            const int t0 = (hist <= 1) ? 0 : hist;  // quirk: hist==1 reruns full prefix
            for (int t = t0; t <= r; ++t) lstm_step(t);

            // ---- hist-end: K[hist], u, (Q if last), log-softmax V -> LDS ----
            f16x8 Bk[4], Bo[4], Bq[4];
#pragma unroll
            for (int kt = 0; kt < 4; ++kt) Bk[kt] = *(const f16x8*)(Wkf + (((w * 4 + kt) * 64 + lane) << 3));
            if (w < 4) {
#pragma unroll
                for (int kt = 0; kt < 4; ++kt) Bo[kt] = *(const f16x8*)(Wo1f + (((w * 4 + kt) * 64 + lane) << 3));
            }
            if (hist == r) {
#pragma unroll
                for (int kt = 0; kt < 4; ++kt) Bq[kt] = *(const f16x8*)(Wqf + (((w * 4 + kt) * 64 + lane) << 3));
            }
            const float bkv  = bk[w * 16 + ml];
            const float bo1v = (w < 4) ? bo1[w * 16 + ml] : 0.0f;
            __syncthreads();   // h1 (hA1[p]) visible to all
            const f16* h1c = &hA1[p][0];
            {
                f32x4 C = f32x4{bkv, bkv, bkv, bkv};
#pragma unroll
                for (int kt = 0; kt < 4; ++kt) C = MFMA16(readA(h1c, kt), Bk[kt], C);
#pragma unroll
                for (int r4 = 0; r4 < 4; ++r4) Ksh[hist][(qh * 4 + r4) * 136 + w * 16 + ml] = (f16)C[r4];
            }
            if (w < 4) {
                f32x4 C = f32x4{bo1v, bo1v, bo1v, bo1v};
#pragma unroll
                for (int kt = 0; kt < 4; ++kt) C = MFMA16(readA(h1c, kt), Bo[kt], C);
#pragma unroll
                for (int r4 = 0; r4 < 4; ++r4) us[(qh * 4 + r4) * 68 + w * 16 + ml] = fmaxf(C[r4], 0.f);
            }
            if (hist == r) {
                const float bqv = bq[w * 16 + ml];
                f32x4 C = f32x4{bqv, bqv, bqv, bqv};
#pragma unroll
                for (int kt = 0; kt < 4; ++kt) C = MFMA16(readA(h1c, kt), Bq[kt], C);
#pragma unroll
                for (int r4 = 0; r4 < 4; ++r4) qsm[(qh * 4 + r4) * 132 + w * 16 + ml] = C[r4];
            }
            __syncthreads();   // us / Ksh / qsm visible
            if (tid < 16) {    // V head: v = logsoftmax(u @ Wo2^T + bo2)
                float v0 = wo2s[128], v1 = wo2s[129];
                const float* up = us + tid * 68;
#pragma unroll 8
                for (int k = 0; k < 64; ++k) {
                    float uu = up[k];
                    v0 = fmaf(uu, wo2s[k], v0);
                    v1 = fmaf(uu, wo2s[64 + k], v1);
                }
                float mv = fmaxf(v0, v1);
                float lse = mv + __logf(__expf(v0 - mv) + __expf(v1 - mv));
                vsh[hist][tid][0] = v0 - lse;
                vsh[hist][tid][1] = v1 - lse;
            }
            if (hist == r && tid < 16 * (r + 1)) {   // raw scores (waves 0..2)
                int row = tid & 15, kk = tid >> 4;
                const float* qp = qsm + row * 132;
                const f16* kp = &Ksh[kk][row * 136];
                float pacc = 0.f;
                for (int k = 0; k < 128; ++k) pacc += qp[k] * (float)kp[k];
                scs[row][kk] = pacc * 0.088388347648318447f;   // 1/sqrt(128)
            }
        }
        // ---------------- round-end: softmax + output ----------------
        __syncthreads();
        if (tid < 16) {
            float mx = -3.4e38f;
            for (int kk = 0; kk <= r; ++kk) mx = fmaxf(mx, scs[tid][kk]);
            float sum = 0.f;
            for (int kk = 0; kk <= r; ++kk) sum += __expf(scs[tid][kk] - mx);
            float inv = 1.0f / sum;
            float o0 = 0.f, o1 = 0.f;
            for (int kk = 0; kk <= r; ++kk) {
                float pp = __expf(scs[tid][kk] - mx) * inv;
                scs[tid][kk] = pp;
                o0 = fmaf(pp, vsh[kk][tid][0], o0);
                o1 = fmaf(pp, vsh[kk][tid][1], o1);
            }
            out[(size_t)(b0 + tid) * 20 + r * 2 + 0] = o0;
            out[(size_t)(b0 + tid) * 20 + r * 2 + 1] = o1;
        }
        __syncthreads();
        if (tid < 160) {   // attention output with -1 padding
            int row = tid / 10, jp = tid - row * 10;
            out[OFF_ATT + (size_t)(b0 + row) * 100 + (size_t)r * 10 + jp] = (jp <= r) ? scs[row][jp] : -1.0f;
        }
    }

    // final h (from f16 LDS state), c (f32 regs)
#pragma unroll
    for (int r4 = 0; r4 < 4; ++r4) {
        int row = qh * 4 + r4;
        int b = b0 + row, hj = w * 16 + ml;
        int ke = row * 128 + (hj ^ ((row & 7) << 3));
        out[OFF_H + (size_t)b * 128 + hj]          = (float)hA0[p][ke];
        out[OFF_H + 131072 + (size_t)b * 128 + hj] = (float)hA1[p][ke];
        out[OFF_C + (size_t)b * 128 + hj]          = c0v[r4];
        out[OFF_C + 131072 + (size_t)b * 128 + hj] = c1v[r4];
    }
}

// ---------------- launch ----------------
extern "C" void kernel_launch(void* const* d_in, const int* in_sizes, int n_in,
                              void* d_out, int out_size, void* d_ws, size_t ws_size,
                              hipStream_t stream) {
    const float* input_vec = (const float*)d_in[0];
    const float* gv    = (const float*)d_in[1];
    const float* uv    = (const float*)d_in[2];
    const float* W_in1 = (const float*)d_in[3];
    const float* b_in1 = (const float*)d_in[4];
    const float* W_in2 = (const float*)d_in[5];
    const float* b_in2 = (const float*)d_in[6];
    const float* Wq    = (const float*)d_in[7];
    const float* bq    = (const float*)d_in[8];
    const float* Wk    = (const float*)d_in[9];
    const float* bk    = (const float*)d_in[10];
    const float* Wih   = (const float*)d_in[11];
    const float* Whh   = (const float*)d_in[12];
    const float* bih   = (const float*)d_in[13];
    const float* bhh   = (const float*)d_in[14];
    const float* Wo1   = (const float*)d_in[15];
    const float* bo1   = (const float*)d_in[16];
    const float* Wo2   = (const float*)d_in[17];
    const float* bo2   = (const float*)d_in[18];
    float* out = (float*)d_out;
    float* ws  = (float*)d_ws;

    // workspace layout (float units)
    float* tmp1    = ws + 0;           // [10240][1024] (dead after gemm2)
    float* xg0     = ws + 0;           // [10240][512]  (gemm3 out, over tmp1)
    float* xgr     = ws + 5242880;     // [64][10][512][16] (inside old tmp1 tail)
    float* lstm_in = ws + 10485760;    // [10240][128]
    f16*   Wf      = (f16*)(ws + 11796480);   // 3 x 65536 f16
    f16*   Wqf     = (f16*)(ws + 11894784);   // 16384 f16
    f16*   Wkf     = (f16*)(ws + 11902976);
    f16*   Wo1f    = (f16*)(ws + 11911168);   // 8192 f16
    float* bias1c  = ws + 11915264;    // [512]
    float* bias0c  = ws + 11915776;    // [512]

    // weight fragment packing + bias combine
    pack_frag_k<<<256, 256, 0, stream>>>(Whh,          Wf,           512, 128); // Whh0
    pack_frag_k<<<256, 256, 0, stream>>>(Wih + 65536,  Wf + 65536,   512, 128); // Wih1
    pack_frag_k<<<256, 256, 0, stream>>>(Whh + 65536,  Wf + 131072,  512, 128); // Whh1
    pack_frag_k<<<64,  256, 0, stream>>>(Wq,  Wqf,  128, 128);
    pack_frag_k<<<64,  256, 0, stream>>>(Wk,  Wkf,  128, 128);
    pack_frag_k<<<32,  256, 0, stream>>>(Wo1, Wo1f, 64,  128);
    bias_comb_k<<<2, 256, 0, stream>>>(bih, bhh, bias0c, bias1c);

    // input MLP + layer-0 input-gate precompute (fp32), then frag-layout reshape
    gemm_bias_act_k<<<dim3(16, 160), 256, 0, stream>>>(input_vec, W_in1, b_in1, tmp1, 10240, 1024, 512, 1);
    gemm_bias_act_k<<<dim3(2, 160), 256, 0, stream>>>(tmp1, W_in2, b_in2, lstm_in, 10240, 128, 1024, 1);
    gemm_bias_act_k<<<dim3(8, 160), 256, 0, stream>>>(lstm_in, Wih, bias0c, xg0, 10240, 512, 128, 0);
    reshape_xg_k<<<20480, 256, 0, stream>>>(xg0, xgr);

    recurrent_mfma6_k<<<64, 512, 0, stream>>>(xgr, Wf, bias1c,
                                              Wqf, bq, Wkf, bk, Wo1f, bo1, Wo2, bo2,
                                              gv, uv, out);
}

// Round 15
// 1374.529 us; speedup vs baseline: 1.8712x; 1.8701x over previous
//
#include <hip/hip_runtime.h>
#include <stdint.h>

// ---------------- constants ----------------
static const size_t OFF_ATT = 20480;    // out: 1024*10*2
static const size_t OFF_H   = 122880;   // + att 1024*10*10
static const size_t OFF_C   = 385024;   // + h 2*1024*128

typedef _Float16 f16;
typedef f16 f16x8 __attribute__((ext_vector_type(8)));
typedef float f32x4 __attribute__((ext_vector_type(4)));

__device__ __forceinline__ float sigf(float x) { return 1.0f / (1.0f + __expf(-x)); }
// tanh(x) = 1 - 2/(e^{2x}+1); safe at +/-inf, ~1e-7 abs err.
__device__ __forceinline__ float tanhfast(float x) { return 1.0f - 2.0f / (__expf(2.0f * x) + 1.0f); }

#define MFMA16(a, b, c) __builtin_amdgcn_mfma_f32_16x16x32_f16((a), (b), (c), 0, 0, 0)

// ---------------- prep kernels ----------------
__global__ void bias_comb_k(const float* __restrict__ bih, const float* __restrict__ bhh,
                            float* __restrict__ b0, float* __restrict__ b1) {
    int i = blockIdx.x * 256 + threadIdx.x;
    if (i < 512) {
        b0[i] = bih[i] + bhh[i];
        b1[i] = bih[512 + i] + bhh[512 + i];
    }
}

// pack f32 W[N][K] (row-major) into f16 B-fragment-linear buffer:
// out[((nt*(K/32)+kt)*64 + lane)*8 + i] = W[nt*16 + (lane&15)][kt*32 + (lane>>4)*8 + i]
__global__ __launch_bounds__(256) void pack_frag_k(const float* __restrict__ W, f16* __restrict__ out,
                                                   int N, int K) {
    int idx = blockIdx.x * 256 + threadIdx.x;
    if (idx >= N * K) return;
    int i = idx & 7, l = (idx >> 3) & 63, rest = idx >> 9;
    int KT = K >> 5;
    int kt = rest % KT, nt = rest / KT;
    int n = nt * 16 + (l & 15);
    int k = kt * 32 + (l >> 4) * 8 + i;
    out[idx] = (f16)W[n * K + k];
}

// xg0[b][t][512] -> xgr[blk][t][col][row16]  (frag-friendly C-init layout)
__global__ __launch_bounds__(256) void reshape_xg_k(const float* __restrict__ xg0, float* __restrict__ xgr) {
    int idx = blockIdx.x * 256 + threadIdx.x;     // 64*10*512*16 = 5242880
    int row16 = idx & 15;
    int col   = (idx >> 4) & 511;
    int tb    = idx >> 13;         // blk*10 + t
    int t     = tb % 10, blk = tb / 10;
    xgr[idx] = xg0[(((size_t)(blk * 16 + row16) * 10 + t) << 9) + col];
}

// ---------------- tiled GEMM: C = act(A[M,K] @ B[N,K]^T + bias[N]) ----------------
__global__ __launch_bounds__(256) void gemm_bias_act_k(const float* __restrict__ A, const float* __restrict__ Bm,
                                                       const float* __restrict__ bias, float* __restrict__ C,
                                                       int M, int N, int K, int relu) {
    __shared__ float As[16][68];
    __shared__ float Bs[16][68];
    int tid = threadIdx.x;
    int tx = tid & 15, ty = tid >> 4;
    int bm = blockIdx.y << 6, bn = blockIdx.x << 6;
    int lr = tid >> 2, lk = (tid & 3) << 2;
    float acc[4][4] = {};
    for (int k0 = 0; k0 < K; k0 += 16) {
        __syncthreads();
        float4 av = *(const float4*)(A + (size_t)(bm + lr) * K + k0 + lk);
        float4 bv = *(const float4*)(Bm + (size_t)(bn + lr) * K + k0 + lk);
        As[lk + 0][lr] = av.x; As[lk + 1][lr] = av.y; As[lk + 2][lr] = av.z; As[lk + 3][lr] = av.w;
        Bs[lk + 0][lr] = bv.x; Bs[lk + 1][lr] = bv.y; Bs[lk + 2][lr] = bv.z; Bs[lk + 3][lr] = bv.w;
        __syncthreads();
#pragma unroll
        for (int kk = 0; kk < 16; ++kk) {
            float a[4], b[4];
#pragma unroll
            for (int i = 0; i < 4; ++i) a[i] = As[kk][ty * 4 + i];
#pragma unroll
            for (int j = 0; j < 4; ++j) b[j] = Bs[kk][tx * 4 + j];
#pragma unroll
            for (int i = 0; i < 4; ++i)
#pragma unroll
                for (int j = 0; j < 4; ++j) acc[i][j] = fmaf(a[i], b[j], acc[i][j]);
        }
    }
#pragma unroll
    for (int i = 0; i < 4; ++i)
#pragma unroll
        for (int j = 0; j < 4; ++j) {
            float v = acc[i][j] + bias[bn + tx * 4 + j];
            if (relu) v = fmaxf(v, 0.0f);
            C[(size_t)(bm + ty * 4 + i) * N + bn + tx * 4 + j] = v;
        }
}

// ---------------- main MFMA recurrent kernel ----------------
// R15 = R10/R14 structure (single barrier/step, incremental K/V attention —
// both correctness-proven) + R5 weight STREAMING (spill-free-proven,
// FETCH=35MB). Weights re-loaded from L2 each step in 3 pipelined groups;
// wbase_s LDS-pointer read blocks LICM from hoisting the (address-invariant)
// loads into persistent registers (the 5x-failed path: R3/R4/R10/R11-13/R14).
__global__ __launch_bounds__(512) void recurrent_mfma7_k(
    const float* __restrict__ xgr,     // [blk][t][col512][row16] f32
    const f16* __restrict__ Wf,        // 3 mats x 512x128 f16 frag-linear (Whh0, Wih1, Whh1)
    const float* __restrict__ bias1,   // [512] bih1+bhh1
    const f16* __restrict__ Wqf, const float* __restrict__ bq,
    const f16* __restrict__ Wkf, const float* __restrict__ bk,
    const f16* __restrict__ Wo1f, const float* __restrict__ bo1,
    const float* __restrict__ Wo2, const float* __restrict__ bo2,
    const float* __restrict__ gv, const float* __restrict__ uv,
    float* __restrict__ out) {
    __shared__ __align__(16) f16 hA0[2][2048];    // 16 rows x 128, XOR-swizzled, dbuf
    __shared__ __align__(16) f16 hA1[2][2048];
    __shared__ __align__(16) f16 Ksh[10][16 * 136];
    __shared__ float vsh[10][16][2];              // log-softmax'd V per hist
    __shared__ __align__(16) float qsm[16 * 132];
    __shared__ __align__(16) float us[16 * 68];
    __shared__ float scs[16][10];
    __shared__ float wo2s[130];
    __shared__ unsigned long long wbase_s;        // LICM blocker (re-read per step)

    const int tid  = threadIdx.x;
    const int lane = tid & 63;
    const int w    = tid >> 6;        // wave id 0..7
    const int ml   = lane & 15;       // tile row (A/m) / tile col (B/n, D col)
    const int qh   = lane >> 4;       // lane quad -> k-group / D row group
    const int blk  = blockIdx.x;
    const int b0   = blk << 4;

    if (tid < 128) wo2s[tid] = Wo2[tid];
    if (tid < 2)   wo2s[128 + tid] = bo2[tid];
    if (tid == 0)  wbase_s = (unsigned long long)(uintptr_t)Wf;

    float bs1v[4];
#pragma unroll
    for (int g = 0; g < 4; ++g) bs1v[g] = bias1[g * 128 + w * 16 + ml];

    // per-wave/lane constant offset into the frag-linear weight buffers:
    // frag(nt=g*8+w, kt) at g*16384 + w*2048 + kt*512 + lane*8
    const int fo = w * 2048 + lane * 8;

    // ---- state init ----
    float c0v[4], c1v[4];
#pragma unroll
    for (int r4 = 0; r4 < 4; ++r4) {
        int row = qh * 4 + r4;
        int b = b0 + row, hj = w * 16 + ml;
        c0v[r4] = uv[(size_t)b * 128 + hj];
        c1v[r4] = uv[131072 + (size_t)b * 128 + hj];
        int ke = hj ^ ((row & 7) << 3);
        hA0[0][row * 128 + ke] = (f16)gv[(size_t)b * 128 + hj];
        hA1[0][row * 128 + ke] = (f16)gv[131072 + (size_t)b * 128 + hj];
    }
    int p = 0;
    __syncthreads();

    // A-frag read: lane reads A[m=ml][k = kt*32 + qh*8 .. +8] from swizzled tile
    auto readA = [&](const f16* base, int kt) -> f16x8 {
        int e = ml * 128 + (((kt << 5) + (qh << 3)) ^ ((ml & 7) << 3));
        return *(const f16x8*)(base + e);
    };

    auto lstm_step = [&](int t) {
        const f16* wf = (const f16*)(uintptr_t)wbase_s;   // LDS read: blocks LICM
        // ---------- layer 0: gates = h0 @ Whh0^T + xg0 (C-init) ----------
        f32x4 C0, C1, C2, C3;
        {
            const float* xb = xgr + ((((size_t)blk * 10 + t) << 9) << 4);
            int coff = w * 16 + ml;
            C0 = *(const f32x4*)(xb + ((coff      ) << 4) + qh * 4);
            C1 = *(const f32x4*)(xb + ((coff + 128) << 4) + qh * 4);
            C2 = *(const f32x4*)(xb + ((coff + 256) << 4) + qh * 4);
            C3 = *(const f32x4*)(xb + ((coff + 384) << 4) + qh * 4);
        }
        // group 1: stream Whh0 frags (16 x dwordx4 from L2)
        f16x8 F0[4][4];
#pragma unroll
        for (int kt = 0; kt < 4; ++kt)
#pragma unroll
            for (int g = 0; g < 4; ++g)
                F0[kt][g] = *(const f16x8*)(wf + fo + g * 16384 + kt * 512);
        const f16* h0p = &hA0[p][0];
#pragma unroll
        for (int kt = 0; kt < 4; ++kt) {
            f16x8 a = readA(h0p, kt);
            C0 = MFMA16(a, F0[kt][0], C0);
            C1 = MFMA16(a, F0[kt][1], C1);
            C2 = MFMA16(a, F0[kt][2], C2);
            C3 = MFMA16(a, F0[kt][3], C3);
        }
        // group 2: stream Wih1 frags early (latency hides under cell0 + barrier)
        f16x8 F1[4][4];
#pragma unroll
        for (int kt = 0; kt < 4; ++kt)
#pragma unroll
            for (int g = 0; g < 4; ++g)
                F1[kt][g] = *(const f16x8*)(wf + 65536 + fo + g * 16384 + kt * 512);
        f16* h0n = &hA0[p ^ 1][0];
#pragma unroll
        for (int r4 = 0; r4 < 4; ++r4) {
            float cn = sigf(C1[r4]) * c0v[r4] + sigf(C0[r4]) * tanhfast(C2[r4]);
            float hn = sigf(C3[r4]) * tanhfast(cn);
            c0v[r4] = cn;
            int row = qh * 4 + r4;
            h0n[row * 128 + ((w * 16 + ml) ^ ((row & 7) << 3))] = (f16)hn;
        }
        __syncthreads();   // the ONLY barrier per step
        // ---------- layer 1: gates = h0new @ Wih1^T + h1 @ Whh1^T + bias1 ----------
        C0 = f32x4{bs1v[0], bs1v[0], bs1v[0], bs1v[0]};
        C1 = f32x4{bs1v[1], bs1v[1], bs1v[1], bs1v[1]};
        C2 = f32x4{bs1v[2], bs1v[2], bs1v[2], bs1v[2]};
        C3 = f32x4{bs1v[3], bs1v[3], bs1v[3], bs1v[3]};
#pragma unroll
        for (int kt = 0; kt < 4; ++kt) {
            f16x8 a = readA(h0n, kt);
            C0 = MFMA16(a, F1[kt][0], C0);
            C1 = MFMA16(a, F1[kt][1], C1);
            C2 = MFMA16(a, F1[kt][2], C2);
            C3 = MFMA16(a, F1[kt][3], C3);
        }
        // group 3: stream Whh1 frags (latency hides under the Wih1 MFMA chain)
        f16x8 F2[4][4];
#pragma unroll
        for (int kt = 0; kt < 4; ++kt)
#pragma unroll
            for (int g = 0; g < 4; ++g)
                F2[kt][g] = *(const f16x8*)(wf + 131072 + fo + g * 16384 + kt * 512);
        const f16* h1p = &hA1[p][0];
#pragma unroll
        for (int kt = 0; kt < 4; ++kt) {
            f16x8 a = readA(h1p, kt);
            C0 = MFMA16(a, F2[kt][0], C0);
            C1 = MFMA16(a, F2[kt][1], C1);
            C2 = MFMA16(a, F2[kt][2], C2);
            C3 = MFMA16(a, F2[kt][3], C3);
        }
        f16* h1n = &hA1[p ^ 1][0];
#pragma unroll
        for (int r4 = 0; r4 < 4; ++r4) {
            float cn = sigf(C1[r4]) * c1v[r4] + sigf(C0[r4]) * tanhfast(C2[r4]);
            float hn = sigf(C3[r4]) * tanhfast(cn);
            c1v[r4] = cn;
            int row = qh * 4 + r4;
            h1n[row * 128 + ((w * 16 + ml) ^ ((row & 7) << 3))] = (f16)hn;
        }
        p ^= 1;            // no end-of-step barrier (dbuf + next mid-step barrier order hazards)
    };

    for (int r = 0; r < 10; ++r) {
        for (int hist = 0; hist <= r; ++hist) {
            const int t0 = (hist <= 1) ? 0 : hist;  // quirk: hist==1 reruns full prefix
            for (int t = t0; t <= r; ++t) lstm_step(t);

            // ---- hist-end: K[hist], u, (Q if last), log-softmax V -> LDS ----
            f16x8 Bk[4], Bo[4], Bq[4];
#pragma unroll
            for (int kt = 0; kt < 4; ++kt) Bk[kt] = *(const f16x8*)(Wkf + (((w * 4 + kt) * 64 + lane) << 3));
            if (w < 4) {
#pragma unroll
                for (int kt = 0; kt < 4; ++kt) Bo[kt] = *(const f16x8*)(Wo1f + (((w * 4 + kt) * 64 + lane) << 3));
            }
            if (hist == r) {
#pragma unroll
                for (int kt = 0; kt < 4; ++kt) Bq[kt] = *(const f16x8*)(Wqf + (((w * 4 + kt) * 64 + lane) << 3));
            }
            const float bkv  = bk[w * 16 + ml];
            const float bo1v = (w < 4) ? bo1[w * 16 + ml] : 0.0f;
            __syncthreads();   // h1 (hA1[p]) visible to all
            const f16* h1c = &hA1[p][0];
            {
                f32x4 C = f32x4{bkv, bkv, bkv, bkv};
#pragma unroll
                for (int kt = 0; kt < 4; ++kt) C = MFMA16(readA(h1c, kt), Bk[kt], C);
#pragma unroll
                for (int r4 = 0; r4 < 4; ++r4) Ksh[hist][(qh * 4 + r4) * 136 + w * 16 + ml] = (f16)C[r4];
            }
            if (w < 4) {
                f32x4 C = f32x4{bo1v, bo1v, bo1v, bo1v};
#pragma unroll
                for (int kt = 0; kt < 4; ++kt) C = MFMA16(readA(h1c, kt), Bo[kt], C);
#pragma unroll
                for (int r4 = 0; r4 < 4; ++r4) us[(qh * 4 + r4) * 68 + w * 16 + ml] = fmaxf(C[r4], 0.f);
            }
            if (hist == r) {
                const float bqv = bq[w * 16 + ml];
                f32x4 C = f32x4{bqv, bqv, bqv, bqv};
#pragma unroll
                for (int kt = 0; kt < 4; ++kt) C = MFMA16(readA(h1c, kt), Bq[kt], C);
#pragma unroll
                for (int r4 = 0; r4 < 4; ++r4) qsm[(qh * 4 + r4) * 132 + w * 16 + ml] = C[r4];
            }
            __syncthreads();   // us / Ksh / qsm visible
            if (tid < 16) {    // V head: v = logsoftmax(u @ Wo2^T + bo2)
                float v0 = wo2s[128], v1 = wo2s[129];
                const float* up = us + tid * 68;
#pragma unroll 8
                for (int k = 0; k < 64; ++k) {
                    float uu = up[k];
                    v0 = fmaf(uu, wo2s[k], v0);
                    v1 = fmaf(uu, wo2s[64 + k], v1);
                }
                float mv = fmaxf(v0, v1);
                float lse = mv + __logf(__expf(v0 - mv) + __expf(v1 - mv));
                vsh[hist][tid][0] = v0 - lse;
                vsh[hist][tid][1] = v1 - lse;
            }
            if (hist == r && tid < 16 * (r + 1)) {   // raw scores (waves 0..2)
                int row = tid & 15, kk = tid >> 4;
                const float* qp = qsm + row * 132;
                const f16* kp = &Ksh[kk][row * 136];
                float pacc = 0.f;
                for (int k = 0; k < 128; ++k) pacc += qp[k] * (float)kp[k];
                scs[row][kk] = pacc * 0.088388347648318447f;   // 1/sqrt(128)
            }
        }
        // ---------------- round-end: softmax + output ----------------
        __syncthreads();
        if (tid < 16) {
            float mx = -3.4e38f;
            for (int kk = 0; kk <= r; ++kk) mx = fmaxf(mx, scs[tid][kk]);
            float sum = 0.f;
            for (int kk = 0; kk <= r; ++kk) sum += __expf(scs[tid][kk] - mx);
            float inv = 1.0f / sum;
            float o0 = 0.f, o1 = 0.f;
            for (int kk = 0; kk <= r; ++kk) {
                float pp = __expf(scs[tid][kk] - mx) * inv;
                scs[tid][kk] = pp;
                o0 = fmaf(pp, vsh[kk][tid][0], o0);
                o1 = fmaf(pp, vsh[kk][tid][1], o1);
            }
            out[(size_t)(b0 + tid) * 20 + r * 2 + 0] = o0;
            out[(size_t)(b0 + tid) * 20 + r * 2 + 1] = o1;
        }
        __syncthreads();
        if (tid < 160) {   // attention output with -1 padding
            int row = tid / 10, jp = tid - row * 10;
            out[OFF_ATT + (size_t)(b0 + row) * 100 + (size_t)r * 10 + jp] = (jp <= r) ? scs[row][jp] : -1.0f;
        }
    }

    // final h (from f16 LDS state), c (f32 regs)
#pragma unroll
    for (int r4 = 0; r4 < 4; ++r4) {
        int row = qh * 4 + r4;
        int b = b0 + row, hj = w * 16 + ml;
        int ke = row * 128 + (hj ^ ((row & 7) << 3));
        out[OFF_H + (size_t)b * 128 + hj]          = (float)hA0[p][ke];
        out[OFF_H + 131072 + (size_t)b * 128 + hj] = (float)hA1[p][ke];
        out[OFF_C + (size_t)b * 128 + hj]          = c0v[r4];
        out[OFF_C + 131072 + (size_t)b * 128 + hj] = c1v[r4];
    }
}

// ---------------- launch ----------------
extern "C" void kernel_launch(void* const* d_in, const int* in_sizes, int n_in,
                              void* d_out, int out_size, void* d_ws, size_t ws_size,
                              hipStream_t stream) {
    const float* input_vec = (const float*)d_in[0];
    const float* gv    = (const float*)d_in[1];
    const float* uv    = (const float*)d_in[2];
    const float* W_in1 = (const float*)d_in[3];
    const float* b_in1 = (const float*)d_in[4];
    const float* W_in2 = (const float*)d_in[5];
    const float* b_in2 = (const float*)d_in[6];
    const float* Wq    = (const float*)d_in[7];
    const float* bq    = (const float*)d_in[8];
    const float* Wk    = (const float*)d_in[9];
    const float* bk    = (const float*)d_in[10];
    const float* Wih   = (const float*)d_in[11];
    const float* Whh   = (const float*)d_in[12];
    const float* bih   = (const float*)d_in[13];
    const float* bhh   = (const float*)d_in[14];
    const float* Wo1   = (const float*)d_in[15];
    const float* bo1   = (const float*)d_in[16];
    const float* Wo2   = (const float*)d_in[17];
    const float* bo2   = (const float*)d_in[18];
    float* out = (float*)d_out;
    float* ws  = (float*)d_ws;

    // workspace layout (float units)
    float* tmp1    = ws + 0;           // [10240][1024] (dead after gemm2)
    float* xg0     = ws + 0;           // [10240][512]  (gemm3 out, over tmp1)
    float* xgr     = ws + 5242880;     // [64][10][512][16] (inside old tmp1 tail)
    float* lstm_in = ws + 10485760;    // [10240][128]
    f16*   Wf      = (f16*)(ws + 11796480);   // 3 x 65536 f16
    f16*   Wqf     = (f16*)(ws + 11894784);   // 16384 f16
    f16*   Wkf     = (f16*)(ws + 11902976);
    f16*   Wo1f    = (f16*)(ws + 11911168);   // 8192 f16
    float* bias1c  = ws + 11915264;    // [512]
    float* bias0c  = ws + 11915776;    // [512]

    // weight fragment packing + bias combine
    pack_frag_k<<<256, 256, 0, stream>>>(Whh,          Wf,           512, 128); // Whh0
    pack_frag_k<<<256, 256, 0, stream>>>(Wih + 65536,  Wf + 65536,   512, 128); // Wih1
    pack_frag_k<<<256, 256, 0, stream>>>(Whh + 65536,  Wf + 131072,  512, 128); // Whh1
    pack_frag_k<<<64,  256, 0, stream>>>(Wq,  Wqf,  128, 128);
    pack_frag_k<<<64,  256, 0, stream>>>(Wk,  Wkf,  128, 128);
    pack_frag_k<<<32,  256, 0, stream>>>(Wo1, Wo1f, 64,  128);
    bias_comb_k<<<2, 256, 0, stream>>>(bih, bhh, bias0c, bias1c);

    // input MLP + layer-0 input-gate precompute (fp32), then frag-layout reshape
    gemm_bias_act_k<<<dim3(16, 160), 256, 0, stream>>>(input_vec, W_in1, b_in1, tmp1, 10240, 1024, 512, 1);
    gemm_bias_act_k<<<dim3(2, 160), 256, 0, stream>>>(tmp1, W_in2, b_in2, lstm_in, 10240, 128, 1024, 1);
    gemm_bias_act_k<<<dim3(8, 160), 256, 0, stream>>>(lstm_in, Wih, bias0c, xg0, 10240, 512, 128, 0);
    reshape_xg_k<<<20480, 256, 0, stream>>>(xg0, xgr);

    recurrent_mfma7_k<<<64, 512, 0, stream>>>(xgr, Wf, bias1c,
                                              Wqf, bq, Wkf, bk, Wo1f, bo1, Wo2, bo2,
                                              gv, uv, out);
}